// Round 1
// baseline (219.452 us; speedup 1.0000x reference)
//
#include <hip/hip_runtime.h>
#include <stdint.h>

typedef unsigned short u16;
typedef unsigned int u32;
typedef short short8 __attribute__((ext_vector_type(8)));
typedef float f32x4 __attribute__((ext_vector_type(4)));
typedef u32 u32x4 __attribute__((ext_vector_type(4)));

#define T_TOT 32768

__device__ __forceinline__ u16 f2bf(float f) {
  u32 u = __float_as_uint(f);
  return (u16)((u + 0x7fffu + ((u >> 16) & 1u)) >> 16);
}
__device__ __forceinline__ float bf2f(u16 h) {
  return __uint_as_float(((u32)h) << 16);
}
__device__ __forceinline__ u32 pk2(float a, float b) {
  return (u32)f2bf(a) | ((u32)f2bf(b) << 16);
}

// ---------------------------------------------------------------------------
// Weight convert fp32 -> bf16, row-major [M][K], 16B-chunk XOR swizzle by row.
// chunk' = (ch & ~7) | ((ch ^ m) & 7)
// ---------------------------------------------------------------------------
__global__ __launch_bounds__(256) void k_wconv(
    const float* __restrict__ fc1, const float* __restrict__ fc2,
    const float* __restrict__ qw, const float* __restrict__ kvw,
    const float* __restrict__ pw, u16* __restrict__ out) {
  int idx = blockIdx.x * 256 + threadIdx.x;  // 32768 chunks total
  const float* src; int K; int rel; u16* dst;
  if (idx < 8192)       { src = fc1; K = 256; rel = idx;         dst = out; }
  else if (idx < 14336) { src = fc2; K = 256; rel = idx - 8192;  dst = out + 65536; }
  else if (idx < 18944) { src = qw;  K = 192; rel = idx - 14336; dst = out + 114688; }
  else if (idx < 28160) { src = kvw; K = 192; rel = idx - 18944; dst = out + 151552; }
  else                  { src = pw;  K = 192; rel = idx - 28160; dst = out + 225280; }
  int nch = K >> 3;
  int m = rel / nch, ch = rel % nch;
  const float* sp = src + (size_t)m * K + ch * 8;
  int pos = (ch & ~7) | ((ch ^ m) & 7);
  u16* dp = dst + (size_t)m * K + pos * 8;
  ushort4 u0, u1;
  u0.x = f2bf(sp[0]); u0.y = f2bf(sp[1]); u0.z = f2bf(sp[2]); u0.w = f2bf(sp[3]);
  u1.x = f2bf(sp[4]); u1.y = f2bf(sp[5]); u1.z = f2bf(sp[6]); u1.w = f2bf(sp[7]);
  *(ushort4*)(dp) = u0;
  *(ushort4*)(dp + 4) = u1;
}

// ---------------------------------------------------------------------------
// Transpose: src fp32 [C][32768] channel-major -> dst bf16 [32768][C]
// token-major, chunk-swizzled (chunk ^= t&7 within 8-chunk groups).
// ---------------------------------------------------------------------------
template<int C>
__global__ __launch_bounds__(256) void k_transpose(const float* __restrict__ src,
                                                   u16* __restrict__ dst) {
  __shared__ u16 sT[64][72];  // [c_local][t_local], padded
  int c0 = blockIdx.x * 64, t0 = blockIdx.y * 64;
  int tid = threadIdx.x;
  for (int i = tid; i < 1024; i += 256) {
    int row = i >> 4;             // c-local
    int tb  = (i & 15) * 4;       // t-local base
    const float* sp = src + (size_t)(c0 + row) * T_TOT + t0 + tb;
    float4 v = *(const float4*)sp;
    ushort4 u;
    u.x = f2bf(v.x); u.y = f2bf(v.y); u.z = f2bf(v.z); u.w = f2bf(v.w);
    *(ushort4*)(&sT[row][tb]) = u;
  }
  __syncthreads();
  int tl = tid & 63;
  int jb = tid >> 6;
  for (int p = 0; p < 2; ++p) {
    int j = jb + 4 * p;           // c-chunk local (0..7)
    int t = t0 + tl;
    u16 e[8];
#pragma unroll
    for (int e8 = 0; e8 < 8; ++e8) e[e8] = sT[j * 8 + e8][tl];
    int pos = (c0 >> 3) + (j ^ (t & 7));
    uint4 o;
    o.x = (u32)e[0] | ((u32)e[1] << 16);
    o.y = (u32)e[2] | ((u32)e[3] << 16);
    o.z = (u32)e[4] | ((u32)e[5] << 16);
    o.w = (u32)e[6] | ((u32)e[7] << 16);
    *(uint4*)(dst + (size_t)t * C + pos * 8) = o;
  }
}

// ---------------------------------------------------------------------------
// GEMM: out(M x 32768) = W(MxK) * Bt^T  (Bt is [32768][K] token-major swizzled)
// Block: 64 m x 128 t, 4 waves (2x2), BK=64 staging. Epilogue variants.
// ---------------------------------------------------------------------------
enum { EPI_FC1 = 0, EPI_FC2 = 1, EPI_Q = 2, EPI_KV = 3, EPI_PROJ = 4 };

template<int M, int K, int EPI>
__global__ __launch_bounds__(256) void k_gemm(const u16* __restrict__ W,
    const u16* __restrict__ B, const float* __restrict__ bias,
    u16* __restrict__ out, u16* __restrict__ out2) {
  __shared__ u16 lW[64 * 64];
  __shared__ u16 lB[128 * 64];
  int tid = threadIdx.x;
  int lane = tid & 63, wid = tid >> 6;
  int g = lane >> 4, c = lane & 15;
  int wm = wid >> 1, wt = wid & 1;
  int t0 = blockIdx.x * 128, m0 = blockIdx.y * 64;
  f32x4 acc[2][4];
#pragma unroll
  for (int i = 0; i < 2; ++i)
#pragma unroll
    for (int j = 0; j < 4; ++j) acc[i][j] = f32x4{0.f, 0.f, 0.f, 0.f};

  for (int s = 0; s < K / 64; ++s) {
    __syncthreads();
    for (int i = tid; i < 512; i += 256) {
      int r = i >> 3, ch = i & 7;
      *(uint4*)(lW + r * 64 + ch * 8) =
          *(const uint4*)(W + (size_t)(m0 + r) * K + s * 64 + ch * 8);
    }
    for (int i = tid; i < 1024; i += 256) {
      int r = i >> 3, ch = i & 7;
      *(uint4*)(lB + r * 64 + ch * 8) =
          *(const uint4*)(B + (size_t)(t0 + r) * K + s * 64 + ch * 8);
    }
    __syncthreads();
#pragma unroll
    for (int kc = 0; kc < 2; ++kc) {
      short8 af[2], bfr[4];
#pragma unroll
      for (int mt = 0; mt < 2; ++mt) {
        int r = wm * 32 + mt * 16 + c;
        af[mt] = *(const short8*)(lW + r * 64 + (((kc * 4 + g) ^ (r & 7)) << 3));
      }
#pragma unroll
      for (int tt = 0; tt < 4; ++tt) {
        int r = wt * 64 + tt * 16 + c;
        bfr[tt] = *(const short8*)(lB + r * 64 + (((kc * 4 + g) ^ (r & 7)) << 3));
      }
#pragma unroll
      for (int mt = 0; mt < 2; ++mt)
#pragma unroll
        for (int tt = 0; tt < 4; ++tt)
          acc[mt][tt] = __builtin_amdgcn_mfma_f32_16x16x32_bf16(
              af[mt], bfr[tt], acc[mt][tt], 0, 0, 0);
    }
  }

  // Epilogue. D layout: row m = m_base + r (r=0..3), col t. m_base = .. + 4g.
#pragma unroll
  for (int mt = 0; mt < 2; ++mt) {
    int m_base = m0 + wm * 32 + mt * 16 + 4 * g;
    float br[4];
    if constexpr (EPI == EPI_KV) {
      if (m_base < 192) { br[0] = br[1] = br[2] = br[3] = 0.f; }
      else {
        float4 b4 = *(const float4*)(bias + (m_base - 192));
        br[0] = b4.x; br[1] = b4.y; br[2] = b4.z; br[3] = b4.w;
      }
    } else {
      float4 b4 = *(const float4*)(bias + m_base);
      br[0] = b4.x; br[1] = b4.y; br[2] = b4.z; br[3] = b4.w;
    }
#pragma unroll
    for (int tt = 0; tt < 4; ++tt) {
      int t = t0 + wt * 64 + tt * 16 + c;
      float v[4];
#pragma unroll
      for (int r = 0; r < 4; ++r) v[r] = acc[mt][tt][r] + br[r];
      if constexpr (EPI == EPI_FC1) {
#pragma unroll
        for (int r = 0; r < 4; ++r)
          v[r] = 0.5f * v[r] * (1.0f + erff(v[r] * 0.70710678118654752f));
      }
      if constexpr (EPI == EPI_FC1 || EPI == EPI_FC2) {
        ushort4 u;
        u.x = f2bf(v[0]); u.y = f2bf(v[1]); u.z = f2bf(v[2]); u.w = f2bf(v[3]);
        int pos = (m_base >> 3) ^ (t & 7);
        *(ushort4*)(out + (size_t)t * M + (pos << 3) + (m_base & 7)) = u;
      } else if constexpr (EPI == EPI_PROJ) {
        ushort4 u;
        u.x = f2bf(v[0]); u.y = f2bf(v[1]); u.z = f2bf(v[2]); u.w = f2bf(v[3]);
        *(ushort4*)(out + (size_t)t * 192 + m_base) = u;  // unswizzled token-major
      } else {  // EPI_Q / EPI_KV window layouts
        int z = t >> 10, y = (t >> 5) & 31, xx = t & 31;
        int win = ((z >> 3) << 4) + ((y >> 3) << 2) + (xx >> 3);
        int n = ((z & 7) << 6) + ((y & 7) << 3) + (xx & 7);
        if (EPI == EPI_Q || m_base < 192) {
          int head = m_base >> 5, dim = m_base & 31;
          ushort4 u;
          u.x = f2bf(v[0]); u.y = f2bf(v[1]); u.z = f2bf(v[2]); u.w = f2bf(v[3]);
          *(ushort4*)(out + ((size_t)(win * 6 + head) * 512 + n) * 32 + dim) = u;
        } else {
          int vb = m_base - 192;
          int head = vb >> 5, dimb = vb & 31;
#pragma unroll
          for (int r = 0; r < 4; ++r) {
            int dimr = dimb + r;
            out2[((size_t)(win * 6 + head) * 32 + dimr) * 512 +
                 (((n >> 3) ^ (dimr & 7)) << 3) + (n & 7)] = f2bf(v[r]);
          }
        }
      }
    }
  }
}

// ---------------------------------------------------------------------------
// Windowed cosine attention. Block = (win, head), 256 threads = 4 waves.
// S^T = mfma(Kn, Qn): lane owns one q-column -> in-register softmax.
// ---------------------------------------------------------------------------
__global__ __launch_bounds__(256) void k_attn(const u16* __restrict__ Qw,
    const u16* __restrict__ Kw, const u16* __restrict__ Vw,
    const float* __restrict__ ls, u16* __restrict__ Amat) {
  extern __shared__ char smem[];
  u16* Kn = (u16*)smem;             // [512][32] token-major
  u16* Vt = (u16*)(smem + 32768);   // [32][512] dim-major, chunk-swizzled
  u16* Pb0 = (u16*)(smem + 65536);  // 4 waves x 2 bufs x 512 u16
  int tid = threadIdx.x, lane = tid & 63, wid = tid >> 6;
  int g = lane >> 4, c = lane & 15;
  int win = blockIdx.x, head = blockIdx.y;
  const u16* Kg = Kw + (size_t)(win * 6 + head) * 16384;
  const u16* Vg = Vw + (size_t)(win * 6 + head) * 16384;
  const u16* Qg = Qw + (size_t)(win * 6 + head) * 16384;
  for (int i = tid; i < 2048; i += 256)
    *(uint4*)(Kn + i * 8) = *(const uint4*)(Kg + i * 8);
  for (int i = tid; i < 2048; i += 256)
    *(uint4*)(Vt + i * 8) = *(const uint4*)(Vg + i * 8);
  __syncthreads();

  // normalize K rows in LDS (fp32 math)
#pragma unroll
  for (int rep = 0; rep < 2; ++rep) {
    int row = wid * 128 + rep * 64 + lane;
    float v[32];
#pragma unroll
    for (int i2 = 0; i2 < 4; ++i2) {
      uint4 d = *(const uint4*)(Kn + row * 32 + i2 * 8);
      u32 dd[4] = {d.x, d.y, d.z, d.w};
#pragma unroll
      for (int q2 = 0; q2 < 4; ++q2) {
        v[i2 * 8 + q2 * 2]     = bf2f((u16)(dd[q2] & 0xffffu));
        v[i2 * 8 + q2 * 2 + 1] = bf2f((u16)(dd[q2] >> 16));
      }
    }
    float ss = 0.f;
#pragma unroll
    for (int e = 0; e < 32; ++e) ss += v[e] * v[e];
    float rn = 1.0f / fmaxf(sqrtf(ss), 1e-12f);
#pragma unroll
    for (int i2 = 0; i2 < 4; ++i2) {
      uint4 d;
      d.x = pk2(v[i2 * 8 + 0] * rn, v[i2 * 8 + 1] * rn);
      d.y = pk2(v[i2 * 8 + 2] * rn, v[i2 * 8 + 3] * rn);
      d.z = pk2(v[i2 * 8 + 4] * rn, v[i2 * 8 + 5] * rn);
      d.w = pk2(v[i2 * 8 + 6] * rn, v[i2 * 8 + 7] * rn);
      *(uint4*)(Kn + row * 32 + i2 * 8) = d;
    }
  }
  __syncthreads();

  float scale = __expf(fminf(ls[head], 4.6051701859880914f));
  u16* pwav = Pb0 + wid * 1024;
  int wz = win >> 4, wy = (win >> 2) & 3, wx = win & 3;

  for (int qt = 0; qt < 8; ++qt) {
    int q0 = wid * 128 + qt * 16;
    // load+normalize q fragment (B-operand): lane reads q row q0+c, dims 8g..8g+7
    uint4 qraw = *(const uint4*)(Qg + (size_t)(q0 + c) * 32 + g * 8);
    u32 qd[4] = {qraw.x, qraw.y, qraw.z, qraw.w};
    float qv[8];
#pragma unroll
    for (int q2 = 0; q2 < 4; ++q2) {
      qv[q2 * 2]     = bf2f((u16)(qd[q2] & 0xffffu));
      qv[q2 * 2 + 1] = bf2f((u16)(qd[q2] >> 16));
    }
    float ss = 0.f;
#pragma unroll
    for (int e = 0; e < 8; ++e) ss += qv[e] * qv[e];
    ss += __shfl_xor(ss, 16);
    ss += __shfl_xor(ss, 32);
    float rn = scale / fmaxf(sqrtf(ss), 1e-12f);
    u32x4 qpk;
    qpk[0] = pk2(qv[0] * rn, qv[1] * rn);
    qpk[1] = pk2(qv[2] * rn, qv[3] * rn);
    qpk[2] = pk2(qv[4] * rn, qv[5] * rn);
    qpk[3] = pk2(qv[6] * rn, qv[7] * rn);
    short8 qf = __builtin_bit_cast(short8, qpk);

    // S^T: D[n'][q], 32 tiles of 16 n' each
    f32x4 s[32];
#pragma unroll
    for (int tt = 0; tt < 32; ++tt) {
      short8 kf = *(const short8*)(Kn + (size_t)(tt * 16 + c) * 32 + g * 8);
      s[tt] = __builtin_amdgcn_mfma_f32_16x16x32_bf16(kf, qf,
                                                      f32x4{0.f, 0.f, 0.f, 0.f}, 0, 0, 0);
    }
    // softmax over n' (128 regs + 2 shuffles)
    float mx = -1e30f;
#pragma unroll
    for (int tt = 0; tt < 32; ++tt)
#pragma unroll
      for (int r = 0; r < 4; ++r) mx = fmaxf(mx, s[tt][r]);
    mx = fmaxf(mx, __shfl_xor(mx, 16));
    mx = fmaxf(mx, __shfl_xor(mx, 32));
    float sum = 0.f;
#pragma unroll
    for (int tt = 0; tt < 32; ++tt)
#pragma unroll
      for (int r = 0; r < 4; ++r) {
        float p = __expf(s[tt][r] - mx);
        s[tt][r] = p;
        sum += p;
      }
    sum += __shfl_xor(sum, 16);
    sum += __shfl_xor(sum, 32);
    float rs = 1.0f / sum;

    // PV: O[q][dim] accumulated over 16 k-chunks of 32 n'
    f32x4 o[2];
    o[0] = f32x4{0.f, 0.f, 0.f, 0.f};
    o[1] = f32x4{0.f, 0.f, 0.f, 0.f};
#pragma unroll
    for (int kc = 0; kc < 16; ++kc) {
      u16* pb = pwav + (kc & 1) * 512;
#pragma unroll
      for (int h = 0; h < 2; ++h) {
        int tt = kc * 2 + h;
        uint2 w2;
        w2.x = pk2(s[tt][0] * rs, s[tt][1] * rs);
        w2.y = pk2(s[tt][2] * rs, s[tt][3] * rs);
        *(uint2*)(pb + c * 32 + h * 16 + g * 4) = w2;
      }
      asm volatile("s_waitcnt lgkmcnt(0)" ::: "memory");
      short8 pf = *(const short8*)(pb + c * 32 + g * 8);
#pragma unroll
      for (int ct = 0; ct < 2; ++ct) {
        short8 vf = *(const short8*)(Vt + (size_t)(ct * 16 + c) * 512 +
                                     (((kc * 4 + g) ^ (c & 7)) << 3));
        o[ct] = __builtin_amdgcn_mfma_f32_16x16x32_bf16(pf, vf, o[ct], 0, 0, 0);
      }
    }
    // write A[t][cg] (token-major, chunk-swizzled)
#pragma unroll
    for (int ct = 0; ct < 2; ++ct) {
      int cg = head * 32 + ct * 16 + c;
#pragma unroll
      for (int r = 0; r < 4; ++r) {
        int n = q0 + 4 * g + r;
        int dz = n >> 6, dy = (n >> 3) & 7, dx = n & 7;
        int t = (wz * 8 + dz) * 1024 + (wy * 8 + dy) * 32 + wx * 8 + dx;
        Amat[(size_t)t * 192 + (((cg >> 3) ^ (t & 7)) << 3) + (cg & 7)] =
            f2bf(o[ct][r]);
      }
    }
  }
}

// ---------------------------------------------------------------------------
// Residual + LayerNorm: out[c][t] = x[c][t] + LN(O2[t][:])*g + b
// ---------------------------------------------------------------------------
__global__ __launch_bounds__(256) void k_ln(const u16* __restrict__ O2,
    const float* __restrict__ x, const float* __restrict__ gg,
    const float* __restrict__ bb, float* __restrict__ out) {
  __shared__ float sO[64][201];
  __shared__ float sm_[64], sr_[64];
  int tid = threadIdx.x;
  int t0 = blockIdx.x * 64;
  for (int i = tid; i < 1536; i += 256) {
    int row = i / 24, c16 = i % 24;
    uint4 d = *(const uint4*)(O2 + (size_t)(t0 + row) * 192 + c16 * 8);
    u32 dd[4] = {d.x, d.y, d.z, d.w};
#pragma unroll
    for (int q2 = 0; q2 < 4; ++q2) {
      sO[row][c16 * 8 + q2 * 2]     = bf2f((u16)(dd[q2] & 0xffffu));
      sO[row][c16 * 8 + q2 * 2 + 1] = bf2f((u16)(dd[q2] >> 16));
    }
  }
  __syncthreads();
  int tk = tid >> 2, part = tid & 3;
  float s1 = 0.f, s2 = 0.f;
  for (int i = 0; i < 48; ++i) {
    float v = sO[tk][part * 48 + i];
    s1 += v;
    s2 += v * v;
  }
  s1 += __shfl_xor(s1, 1); s1 += __shfl_xor(s1, 2);
  s2 += __shfl_xor(s2, 1); s2 += __shfl_xor(s2, 2);
  float mean = s1 * (1.0f / 192.0f);
  float var = s2 * (1.0f / 192.0f) - mean * mean;
  float rstd = rsqrtf(var + 1e-5f);
  if (part == 0) { sm_[tk] = mean; sr_[tk] = rstd; }
  __syncthreads();
  for (int i = tid; i < 12288; i += 256) {
    int cc = i >> 6, tl = i & 63;
    size_t gi = (size_t)cc * T_TOT + t0 + tl;
    out[gi] = x[gi] + (sO[tl][cc] - sm_[tl]) * sr_[tl] * gg[cc] + bb[cc];
  }
}

// ---------------------------------------------------------------------------
extern "C" void kernel_launch(void* const* d_in, const int* in_sizes, int n_in,
                              void* d_out, int out_size, void* d_ws, size_t ws_size,
                              hipStream_t stream) {
  const float* x      = (const float*)d_in[0];
  const float* prev   = (const float*)d_in[1];
  const float* fc1_w  = (const float*)d_in[2];
  const float* fc1_b  = (const float*)d_in[3];
  const float* fc2_w  = (const float*)d_in[4];
  const float* fc2_b  = (const float*)d_in[5];
  const float* q_w    = (const float*)d_in[6];
  const float* q_b    = (const float*)d_in[7];
  const float* kv_w   = (const float*)d_in[8];
  const float* v_b    = (const float*)d_in[9];
  const float* proj_w = (const float*)d_in[10];
  const float* proj_b = (const float*)d_in[11];
  const float* lsc    = (const float*)d_in[12];
  const float* ln_g   = (const float*)d_in[13];
  const float* ln_b   = (const float*)d_in[14];
  float* out = (float*)d_out;
  char* ws = (char*)d_ws;

  u16* Pt   = (u16*)(ws + 0);          // [32768][256] bf16 swz   (16 MiB)
  u16* Y1t  = (u16*)(ws + 16777216);   // [32768][256]            (16 MiB)
  u16* Zt   = (u16*)(ws + 33554432);   // [32768][192]            (12 MiB)
  u16* Xt   = (u16*)(ws + 46137344);   // [32768][192]            (12 MiB)
  u16* Kwin = (u16*)(ws + 58720256);   // [64][6][512][32]        (12 MiB)
  u16* Vwin = (u16*)(ws + 71303168);   // [64][6][32][512] swz    (12 MiB)
  u16* Wbf  = (u16*)(ws + 83886080);   // 262144 bf16 weights
  u16* Qwin = Pt;    // alias: Pt dead after fc1
  u16* Amat = Y1t;   // alias: Y1t dead after fc2
  u16* O2t  = Xt;    // alias: Xt dead after q-GEMM

  k_wconv<<<128, 256, 0, stream>>>(fc1_w, fc2_w, q_w, kv_w, proj_w, Wbf);
  k_transpose<256><<<dim3(4, 512), 256, 0, stream>>>(prev, Pt);
  k_transpose<192><<<dim3(3, 512), 256, 0, stream>>>(x, Xt);
  k_gemm<256, 256, EPI_FC1><<<dim3(256, 4), 256, 0, stream>>>(Wbf, Pt, fc1_b, Y1t, nullptr);
  k_gemm<192, 256, EPI_FC2><<<dim3(256, 3), 256, 0, stream>>>(Wbf + 65536, Y1t, fc2_b, Zt, nullptr);
  k_gemm<192, 192, EPI_Q><<<dim3(256, 3), 256, 0, stream>>>(Wbf + 114688, Xt, q_b, Qwin, nullptr);
  k_gemm<384, 192, EPI_KV><<<dim3(256, 6), 256, 0, stream>>>(Wbf + 151552, Zt, v_b, Kwin, Vwin);
  k_attn<<<dim3(64, 6), 256, 73728, stream>>>(Qwin, Kwin, Vwin, lsc, Amat);
  k_gemm<192, 192, EPI_PROJ><<<dim3(256, 3), 256, 0, stream>>>(Wbf + 225280, Amat, proj_b, O2t, nullptr);
  k_ln<<<512, 256, 0, stream>>>(O2t, x, ln_g, ln_b, out);
}